// Round 8
// baseline (270.090 us; speedup 1.0000x reference)
//
#include <hip/hip_runtime.h>

// Multibin binary conv:  y = conv2d(sign(x), sum_m sign(W_m), SAME) + sum_m b_m
// x: [16,256,256,32] f32   W: [4,3,3,32,32] f32   b: [4,32] f32 -> out f32
//
// Round-8: TWO-PASS decomposition (round-7 structure, slot-ring RACE FIXED).
//   pass1 pack_kernel: x f32 -> xq i8 signs, 48 B/pixel layout (50.3 MB).
//   pass2 conv_packed: implicit GEMM mfma_i32_32x32x32_i8 from xq; per-row
//     staging is 2x global_load_lds DMA directly into the read ring.
//   BUG in round 7: ring of 4 slots but FIVE rows live at once (read i,i+1,i+2;
//   commit i+3; DMA i+4) -> ISSUE_P(i+4) landed in slot (i+4)&3 == i&3, racing
//   the dh=0 ds_reads (and clobbering the zeroed edge halo with OOB garbage ->
//   absmax 2434 > the 2304 bound for +-1 data).  Fix: RING OF 5 (%5, all
//   compile-time).  Slot for row j+5 is reused only after iter j's ds_reads
//   retired (lgkmcnt precedes MFMA use, which precedes next iter's issue).
// Fallback: if ws_size < 50.4 MB, run the proven round-4 fused kernel (85.5us).

#define RH      8
#define PITCHB  48                    // fused path: packed bytes per pixel
#define PSLOT   (34 * PITCHB)         // fused: 1632 B packed row slot (x4)
#define RSLOT   4096                  // fused: raw slot (x3)
#define RAWOFF  (4 * PSLOT)
#define SLOTP   2048                  // packed path: row slot stride (DMA writes 2048 B)
#define NRING   5                     // packed path: 5 live rows -> 5 slots (10 KiB)
#define XQOFF   16384                 // xq offset in ws (wsT 9216 + bsum 128 + pad)
#define XQSZ    50331648              // 16*256*256*48
#define WSNEED  (XQOFF + XQSZ + 4096) // + OOB slack for tail DMA overrun

typedef __attribute__((ext_vector_type(4)))  int i32x4;
typedef __attribute__((ext_vector_type(16))) int i32x16;

__device__ __forceinline__ void gload16(const void* g, void* l) {
    __builtin_amdgcn_global_load_lds(
        (const __attribute__((address_space(1))) void*)g,
        (__attribute__((address_space(3))) void*)l, 16, 0, 0);
}

__device__ __forceinline__ unsigned packsgn4(uint4 v) {
    unsigned r;
    r  =  (__uint_as_float(v.x) >= 0.0f) ? 0x01u : 0xFFu;
    r |= ((__uint_as_float(v.y) >= 0.0f) ? 0x01u : 0xFFu) << 8;
    r |= ((__uint_as_float(v.z) >= 0.0f) ? 0x01u : 0xFFu) << 16;
    r |= ((__uint_as_float(v.w) >= 0.0f) ? 0x01u : 0xFFu) << 24;
    return r;
}

__device__ __forceinline__ unsigned packsgn4f(float4 v) {
    unsigned r;
    r  =  ((v.x >= 0.0f) ? 0x01u : 0xFFu);
    r |= ((v.y >= 0.0f) ? 0x01u : 0xFFu) << 8;
    r |= ((v.z >= 0.0f) ? 0x01u : 0xFFu) << 16;
    r |= ((v.w >= 0.0f) ? 0x01u : 0xFFu) << 24;
    return r;
}

// ---------------- prep: wsT[co][288] i8 + bsum[32] f32 ----------------
__global__ void prep_kernel(const float* __restrict__ W, const float* __restrict__ bias,
                            signed char* __restrict__ wsT, float* __restrict__ bsum) {
    int t = blockIdx.x * 256 + threadIdx.x;
    if (t < 9216) {
        int k   = t >> 5;          // 0..287 = tap*32 + ci
        int co  = t & 31;
        int tap = k >> 5;
        int ci  = k & 31;
        float s = 0.0f;
        #pragma unroll
        for (int m = 0; m < 4; ++m) {
            float w = W[(m * 9 + tap) * 1024 + ci * 32 + co];
            s += (w >= 0.0f) ? 1.0f : -1.0f;
        }
        wsT[co * 288 + k] = (signed char)(int)s;
    }
    if (t < 32) {
        float s = 0.0f;
        #pragma unroll
        for (int m = 0; m < 4; ++m) s += bias[m * 32 + t];
        bsum[t] = s;
    }
}

// ---------------- pass 1: sign-pack x into 48 B/pixel layout ----------------
// 8,388,608 float4 units = 8192 blocks x 256 thr x 4 units (exact)
__global__ __launch_bounds__(256) void pack_kernel(const float* __restrict__ x,
                                                   unsigned char* __restrict__ xq) {
    int t = blockIdx.x * 256 + threadIdx.x;
    #pragma unroll
    for (int it = 0; it < 4; ++it) {
        int idx = t + it * 2097152;
        float4 v = ((const float4*)x)[idx];        // coalesced 16B/lane
        unsigned r = packsgn4f(v);
        int px = idx >> 3, u = idx & 7;            // 8 dwords of signs per pixel
        *(unsigned*)(xq + (long)px * 48 + u * 4) = r;  // bytes 32..47 = pad
    }
}

// counted wait + scheduling fence
#define WAITV(N)                                                                \
    do {                                                                        \
        asm volatile("s_waitcnt vmcnt(" #N ")" ::: "memory");                   \
        __builtin_amdgcn_sched_barrier(0);                                      \
    } while (0)

// ======================= pass 2: conv from packed signs =======================
// stage row J into ring slot J%5: 2x gload16 (lane-linear, 2048 B from xq row
// span; slot holds px c0-1 .. c0+32 at 48 B pitch = first 1632 B; tail is
// harmless overrun within the slot)
#define ISSUE_P(J)                                                              \
    do {                                                                        \
        const int row_  = r0 - 1 + (J);                                         \
        const int rowc_ = row_ < 0 ? 0 : (row_ > 255 ? 255 : row_);             \
        const char* gb_ = (const char*)xq +                                     \
            ((long)(bimg * 256 + rowc_) * 256 + (c0 - 1)) * 48;                 \
        unsigned char* lb_ = lds + ((J) % NRING) * SLOTP;                       \
        gload16(gb_ + lane * 16, lb_);                                          \
        gload16(gb_ + 1024 + lane * 16, lb_ + 1024);                            \
        __builtin_amdgcn_sched_barrier(0);                                      \
    } while (0)

// after the wait: zero invalid rows / edge-column halo pixels (units 0,1 only
// -- MFMA never reads the 16 B pad unit)
#define COMMIT_P(J)                                                             \
    do {                                                                        \
        const int row_   = r0 - 1 + (J);                                        \
        const bool rowok_ = (row_ >= 0) && (row_ < 256);                        \
        unsigned char* sl_ = lds + ((J) % NRING) * SLOTP;                       \
        if (!rowok_) {                                                          \
            if (lane < 34) {                                                    \
                *(uint4*)(sl_ + lane * 48)      = zr4;                          \
                *(uint4*)(sl_ + lane * 48 + 16) = zr4;                          \
            }                                                                   \
        } else if (hz_on) {                                                     \
            *(uint4*)(sl_ + hz_ad) = zr4;                                       \
        }                                                                       \
    } while (0)

__global__ __launch_bounds__(64, 4) void conv_packed(const unsigned char* __restrict__ xq,
                                                     const signed char* __restrict__ wsT,
                                                     const float* __restrict__ bsum,
                                                     float* __restrict__ out) {
    __shared__ __align__(16) unsigned char lds[NRING * SLOTP];   // 10 KiB

    const int lane = threadIdx.x;     // single wave per block
    const int lrow = lane & 31;       // A: output pixel / B,D: cout column
    const int lk   = lane >> 5;       // K-half selector

    const int bs   = blockIdx.x;      // 4096 = 16 img x 32 rowstrips x 8 colstrips
    const int c0   = (bs & 7) * 32;
    const int r0   = ((bs >> 3) & 31) * RH;
    const int bimg = bs >> 8;

    // B fragments + bias (retire under prologue waits)
    i32x4 bfrag[9];
    #pragma unroll
    for (int t = 0; t < 9; ++t)
        bfrag[t] = *(const i32x4*)(wsT + lrow * 288 + t * 32 + lk * 16);
    const float bsv = bsum[lrow];

    const uint4 zr4 = make_uint4(0u, 0u, 0u, 0u);
    // edge-halo zero: lanes 0,1 -> px0 units (left edge), lanes 2,3 -> px33 (right)
    const bool hz_on = ((c0 == 0) && (lane < 2)) ||
                       ((c0 == 224) && (lane >= 2) && (lane < 4));
    const int  hz_ad = (lane < 2) ? lane * 16 : (33 * 48 + (lane - 2) * 16);

    // ---- prologue: rows j0..j2 DMA'd, committed under counted waits ----
    ISSUE_P(0);
    ISSUE_P(1);
    ISSUE_P(2);
    WAITV(4);  COMMIT_P(0);            // bfrag/bias + j0 retired
    WAITV(2);  COMMIT_P(1);
    ISSUE_P(3);
    WAITV(2);  COMMIT_P(2);

    const int a_base = lrow * 48 + lk * 16;

    #pragma unroll
    for (int i = 0; i < RH; ++i) {
        if (i <= RH - 3) ISSUE_P(i + 4);

        // wait for row j=i+3 (issued one iteration back); this iter's 2 fresh
        // loads + previous iter's 16 stores stay outstanding.
        if (i == 0)      { WAITV(2);  }
        else if (i <= 5) { WAITV(18); }
        else if (i == 6) { WAITV(16); }
        if (i <= RH - 2) COMMIT_P(i + 3);

        // ---- MFMA: A-frags read DIRECTLY from ring slots (i,i+1,i+2)%5 ----
        i32x16 acc = {};
        #pragma unroll
        for (int dh = 0; dh < 3; ++dh) {
            const unsigned char* sb = lds + ((i + dh) % NRING) * SLOTP;
            #pragma unroll
            for (int dw = 0; dw < 3; ++dw) {
                i32x4 a = *(const i32x4*)(sb + a_base + dw * 48);
                acc = __builtin_amdgcn_mfma_i32_32x32x32_i8(a, bfrag[dh * 3 + dw],
                                                            acc, 0, 0, 0);
            }
        }

        // ---- store (coalesced full-line scalar, proven in R4) ----
        float* op = out + ((long)((bimg * 256 + (r0 + i)) * 256 + c0)) * 32 + lrow;
        #pragma unroll
        for (int reg = 0; reg < 16; ++reg) {
            int pr = (reg & 3) + 8 * (reg >> 2) + 4 * lk;
            op[pr * 32] = (float)acc[reg] + bsv;
        }
    }
}

// ======================= fallback: round-4 fused kernel =======================
#define HSEL(J) ((((J) % 3) == 0) ? h0 : ((((J) % 3) == 1) ? h1 : h2))

#define ISSUE_ROW(J, HREG)                                                      \
    do {                                                                        \
        const int row_  = r0 - 1 + (J);                                         \
        const int rowc_ = row_ < 0 ? 0 : (row_ > 255 ? 255 : row_);             \
        const char* gb_ = (const char*)(x + (long)((bimg * 256 + rowc_) * 256   \
                                                   + c0) * 32);                 \
        unsigned char* lb_ = lds + RAWOFF + ((J) % 3) * RSLOT;                  \
        _Pragma("unroll")                                                       \
        for (int k_ = 0; k_ < 4; ++k_)                                          \
            gload16(gb_ + k_ * 1024 + lswz16, lb_ + k_ * 1024);                 \
        HREG = *(x + (long)(bimg * 256 + rowc_) * 8192 + hoff);                 \
        __builtin_amdgcn_sched_barrier(0);                                      \
    } while (0)

#define PACK_ROW(J, HREG)                                                       \
    do {                                                                        \
        const int row_   = r0 - 1 + (J);                                        \
        const bool rowok_ = (row_ >= 0) && (row_ < 256);                        \
        unsigned char* ps_ = lds + ((J) & 3) * PSLOT;                           \
        const unsigned char* rs_ = lds + RAWOFF + ((J) % 3) * RSLOT;            \
        ps_[hpx * PITCHB + (lane & 31)] =                                       \
            (rowok_ && hok) ? ((HREG >= 0.0f) ? 0x01 : 0xFF) : 0;               \
        uint4 o_;                                                               \
        if (rowok_) {                                                           \
            uint4 w0_ = *(const uint4*)(rs_ + (ppx * 8 + ((ph * 4 + 0) ^ pxr)) * 16); \
            uint4 w1_ = *(const uint4*)(rs_ + (ppx * 8 + ((ph * 4 + 1) ^ pxr)) * 16); \
            uint4 w2_ = *(const uint4*)(rs_ + (ppx * 8 + ((ph * 4 + 2) ^ pxr)) * 16); \
            uint4 w3_ = *(const uint4*)(rs_ + (ppx * 8 + ((ph * 4 + 3) ^ pxr)) * 16); \
            o_ = make_uint4(packsgn4(w0_), packsgn4(w1_),                       \
                            packsgn4(w2_), packsgn4(w3_));                      \
        } else {                                                                \
            o_ = make_uint4(0u, 0u, 0u, 0u);                                    \
        }                                                                       \
        *(uint4*)(ps_ + (ppx + 1) * PITCHB + ph * 16) = o_;                     \
    } while (0)

__global__ __launch_bounds__(64, 2) void conv_fused(const float* __restrict__ x,
                                                    const signed char* __restrict__ wsT,
                                                    const float* __restrict__ bsum,
                                                    float* __restrict__ out) {
    __shared__ __align__(16) unsigned char lds[4 * PSLOT + 3 * RSLOT];

    const int lane = threadIdx.x;
    const int lrow = lane & 31;
    const int lk   = lane >> 5;

    const int bs   = blockIdx.x;
    const int c0   = (bs & 7) * 32;
    const int r0   = ((bs >> 3) & 31) * RH;
    const int bimg = bs >> 8;

    i32x4 bfrag[9];
    #pragma unroll
    for (int t = 0; t < 9; ++t)
        bfrag[t] = *(const i32x4*)(wsT + lrow * 288 + t * 32 + lk * 16);
    const float bsv = bsum[lrow];

    const int lswz16 = (lane ^ ((lane >> 3) & 7)) * 16;
    const int hcol   = (lane < 32) ? (c0 > 0 ? c0 - 1 : 0)
                                   : (c0 + 32 < 256 ? c0 + 32 : 255);
    const bool hok   = (lane < 32) ? (c0 > 0) : (c0 + 32 < 256);
    const int  hpx   = (lane < 32) ? 0 : 33;
    const long hoff  = (long)hcol * 32 + (lane & 31);
    const int  ppx   = lane >> 1;
    const int  ph    = lane & 1;
    const int  pxr   = ppx & 7;

    float h0 = 0.f, h1 = 0.f, h2 = 0.f;

    ISSUE_ROW(0, HSEL(0));
    ISSUE_ROW(1, HSEL(1));
    ISSUE_ROW(2, HSEL(2));
    WAITV(10);  PACK_ROW(0, HSEL(0));
    WAITV(5);   PACK_ROW(1, HSEL(1));
    ISSUE_ROW(3, HSEL(3));
    WAITV(5);   PACK_ROW(2, HSEL(2));

    const int a_off = lrow * PITCHB + lk * 16;

    #pragma unroll
    for (int i = 0; i < RH; ++i) {
        if (i <= RH - 3) ISSUE_ROW(i + 4, HSEL(i + 4));

        if (i == 0)      { WAITV(5);  }
        else if (i <= 5) { WAITV(21); }
        else if (i == 6) { WAITV(16); }
        if (i <= RH - 2) PACK_ROW(i + 3, HSEL(i + 3));

        i32x16 acc = {};
        #pragma unroll
        for (int dh = 0; dh < 3; ++dh) {
            const unsigned char* sb = lds + ((i + dh) & 3) * PSLOT + a_off;
            #pragma unroll
            for (int dw = 0; dw < 3; ++dw) {
                i32x4 a = *(const i32x4*)(sb + dw * PITCHB);
                acc = __builtin_amdgcn_mfma_i32_32x32x32_i8(a, bfrag[dh * 3 + dw],
                                                            acc, 0, 0, 0);
            }
        }

        float* op = out + ((long)((bimg * 256 + (r0 + i)) * 256 + c0)) * 32 + lrow;
        #pragma unroll
        for (int reg = 0; reg < 16; ++reg) {
            int pr = (reg & 3) + 8 * (reg >> 2) + 4 * lk;
            op[pr * 32] = (float)acc[reg] + bsv;
        }
    }
}

extern "C" void kernel_launch(void* const* d_in, const int* in_sizes, int n_in,
                              void* d_out, int out_size, void* d_ws, size_t ws_size,
                              hipStream_t stream) {
    const float* x    = (const float*)d_in[0];   // [16,256,256,32]
    const float* W    = (const float*)d_in[1];   // [4,3,3,32,32]
    const float* bias = (const float*)d_in[2];   // [4,32]
    float* out = (float*)d_out;

    signed char* wsT  = (signed char*)d_ws;                 // 9216 B
    float* bsum       = (float*)((char*)d_ws + 9216);       // 32 f32
    unsigned char* xq = (unsigned char*)d_ws + XQOFF;       // 50.3 MB packed signs

    prep_kernel<<<36, 256, 0, stream>>>(W, bias, wsT, bsum);
    if (ws_size >= (size_t)WSNEED) {
        pack_kernel<<<8192, 256, 0, stream>>>(x, xq);
        conv_packed<<<4096, 64, 0, stream>>>(xq, wsT, bsum, out);
    } else {
        conv_fused<<<4096, 64, 0, stream>>>(x, wsT, bsum, out);
    }
}

// Round 9
// 257.577 us; speedup vs baseline: 1.0486x; 1.0486x over previous
//
#include <hip/hip_runtime.h>

// Multibin binary conv:  y = conv2d(sign(x), sum_m sign(W_m), SAME) + sum_m b_m
// x: [16,256,256,32] f32   W: [4,3,3,32,32] f32   b: [4,32] f32 -> out f32
//
// Round-9: TWO-PASS with BATCH-STAGED conv (zero loop waits).
//   Evidence from R8: harness ws-poison fill (536 MB) runs at 6.7 TB/s @ 9.4%
//   occupancy -> write path + occupancy exonerated.  conv_packed kept the
//   per-row vmcnt cadence and stayed slow despite L2-hot reads -> the
//   remaining shared invariant across ALL ~85us variants is waiting on
//   memory once per output row.
//   conv_batch: stage ALL 10 packed rows of the strip (20 gload16, 20.5 KB
//   LDS), ONE vmcnt(0) per block, then 8 rows of pure LDS+MFMA+stores with
//   no memory waits at all.  8 blocks/CU (2 waves/SIMD).
//   pack_kernel v2: 2 threads/pixel, dense float4 reads, 48 B/px writes
//   INCLUDING pad -> full-line write streams (no partial-line RMW).
// Fallback: if ws_size < 50.4 MB, run the proven round-4 fused kernel (85.5us).

#define RH      8
#define PITCHB  48                    // fused path: packed bytes per pixel
#define PSLOT   (34 * PITCHB)         // fused: 1632 B packed row slot (x4)
#define RSLOT   4096                  // fused: raw slot (x3)
#define RAWOFF  (4 * PSLOT)
#define SLOTB2  2048                  // batch path: per-row slot (2x 1024B DMA)
#define NSLOT   10                    // batch path: whole strip resident
#define XQOFF   16384                 // xq offset in ws (wsT 9216 + bsum 128 + pad)
#define XQSZ    50331648              // 16*256*256*48
#define WSNEED  (XQOFF + XQSZ + 4096) // + OOB slack for edge DMA overrun

typedef __attribute__((ext_vector_type(4)))  int i32x4;
typedef __attribute__((ext_vector_type(16))) int i32x16;

__device__ __forceinline__ void gload16(const void* g, void* l) {
    __builtin_amdgcn_global_load_lds(
        (const __attribute__((address_space(1))) void*)g,
        (__attribute__((address_space(3))) void*)l, 16, 0, 0);
}

__device__ __forceinline__ unsigned packsgn4(uint4 v) {
    unsigned r;
    r  =  (__uint_as_float(v.x) >= 0.0f) ? 0x01u : 0xFFu;
    r |= ((__uint_as_float(v.y) >= 0.0f) ? 0x01u : 0xFFu) << 8;
    r |= ((__uint_as_float(v.z) >= 0.0f) ? 0x01u : 0xFFu) << 16;
    r |= ((__uint_as_float(v.w) >= 0.0f) ? 0x01u : 0xFFu) << 24;
    return r;
}

__device__ __forceinline__ unsigned packsgn4f(float4 v) {
    unsigned r;
    r  =  ((v.x >= 0.0f) ? 0x01u : 0xFFu);
    r |= ((v.y >= 0.0f) ? 0x01u : 0xFFu) << 8;
    r |= ((v.z >= 0.0f) ? 0x01u : 0xFFu) << 16;
    r |= ((v.w >= 0.0f) ? 0x01u : 0xFFu) << 24;
    return r;
}

// ---------------- prep: wsT[co][288] i8 + bsum[32] f32 ----------------
__global__ void prep_kernel(const float* __restrict__ W, const float* __restrict__ bias,
                            signed char* __restrict__ wsT, float* __restrict__ bsum) {
    int t = blockIdx.x * 256 + threadIdx.x;
    if (t < 9216) {
        int k   = t >> 5;          // 0..287 = tap*32 + ci
        int co  = t & 31;
        int tap = k >> 5;
        int ci  = k & 31;
        float s = 0.0f;
        #pragma unroll
        for (int m = 0; m < 4; ++m) {
            float w = W[(m * 9 + tap) * 1024 + ci * 32 + co];
            s += (w >= 0.0f) ? 1.0f : -1.0f;
        }
        wsT[co * 288 + k] = (signed char)(int)s;
    }
    if (t < 32) {
        float s = 0.0f;
        #pragma unroll
        for (int m = 0; m < 4; ++m) s += bias[m * 32 + t];
        bsum[t] = s;
    }
}

// ---------------- pass 1: sign-pack, 2 threads/pixel, full-line writes ----------
// 2,097,152 threads = 8192 blocks x 256.  thread = (pixel, half).
// reads: 4x dwordx4, lanes at 64 B stride (dense over the 4-instr group).
// writes: 16 B signs at px*48 + half*16; odd half also writes the 16 B pad
// -> every byte of xq written -> full-line streams, no partial-line RMW.
__global__ __launch_bounds__(256) void pack_kernel(const float* __restrict__ x,
                                                   unsigned char* __restrict__ xq) {
    int t  = blockIdx.x * 256 + threadIdx.x;
    int px = t >> 1, h = t & 1;
    const char* src = (const char*)x + (long)px * 128 + h * 64;
    uint4 v0 = *(const uint4*)(src);
    uint4 v1 = *(const uint4*)(src + 16);
    uint4 v2 = *(const uint4*)(src + 32);
    uint4 v3 = *(const uint4*)(src + 48);
    uint4 sg = make_uint4(packsgn4(v0), packsgn4(v1), packsgn4(v2), packsgn4(v3));
    unsigned char* dst = xq + (long)px * 48 + h * 16;
    *(uint4*)dst = sg;
    if (h) *(uint4*)(dst + 16) = make_uint4(0u, 0u, 0u, 0u);   // pad bytes 32..47
}

// counted wait + scheduling fence
#define WAITV(N)                                                                \
    do {                                                                        \
        asm volatile("s_waitcnt vmcnt(" #N ")" ::: "memory");                   \
        __builtin_amdgcn_sched_barrier(0);                                      \
    } while (0)

// ======================= pass 2: batch-staged conv =======================
__global__ __launch_bounds__(64, 2) void conv_batch(const unsigned char* __restrict__ xq,
                                                    const signed char* __restrict__ wsT,
                                                    const float* __restrict__ bsum,
                                                    float* __restrict__ out) {
    __shared__ __align__(16) unsigned char lds[NSLOT * SLOTB2];   // 20480 B

    const int lane = threadIdx.x;     // single wave per block
    const int lrow = lane & 31;       // A: output pixel / B,D: cout column
    const int lk   = lane >> 5;       // K-half selector

    const int bs   = blockIdx.x;      // 4096 = 16 img x 32 rowstrips x 8 colstrips
    const int c0   = (bs & 7) * 32;
    const int r0   = ((bs >> 3) & 31) * RH;
    const int bimg = bs >> 8;

    // ---- issue ALL 10 rows' DMA (20 gload16), fire-and-forget ----
    #pragma unroll
    for (int j = 0; j < NSLOT; ++j) {
        const int row  = r0 - 1 + j;
        const int rowc = row < 0 ? 0 : (row > 255 ? 255 : row);
        const char* gb = (const char*)xq +
            ((long)(bimg * 256 + rowc) * 256 + (c0 - 1)) * 48;
        unsigned char* lb = lds + j * SLOTB2;
        gload16(gb + lane * 16, lb);
        gload16(gb + 1024 + lane * 16, lb + 1024);
    }

    // B fragments + bias (retire under the same single wait)
    i32x4 bfrag[9];
    #pragma unroll
    for (int t = 0; t < 9; ++t)
        bfrag[t] = *(const i32x4*)(wsT + lrow * 288 + t * 32 + lk * 16);
    const float bsv = bsum[lrow];

    // ---- the ONE memory wait of this block ----
    WAITV(0);

    // ---- LDS fixups: zero invalid rows / edge-column halo pixels ----
    const uint4 zr4 = make_uint4(0u, 0u, 0u, 0u);
    #pragma unroll
    for (int j = 0; j < NSLOT; ++j) {
        const int row = r0 - 1 + j;      // only j==0 / j==9 can be out of range
        unsigned char* sl = lds + j * SLOTB2;
        if (row < 0 || row > 255) {
            if (lane < 34) {
                *(uint4*)(sl + lane * 48)      = zr4;
                *(uint4*)(sl + lane * 48 + 16) = zr4;
            }
        } else {
            if ((c0 == 0) && (lane < 2))
                *(uint4*)(sl + lane * 16) = zr4;                  // px0 = col -1
            if ((c0 == 224) && (lane >= 2) && (lane < 4))
                *(uint4*)(sl + 33 * 48 + (lane - 2) * 16) = zr4;  // px33 = col 256
        }
    }

    const int a_base = lrow * 48 + lk * 16;

    // ---- 8 output rows: pure LDS + MFMA + fire-and-forget stores ----
    #pragma unroll
    for (int i = 0; i < RH; ++i) {
        i32x16 acc = {};
        #pragma unroll
        for (int dh = 0; dh < 3; ++dh) {
            const unsigned char* sb = lds + (i + dh) * SLOTB2;    // direct slot
            #pragma unroll
            for (int dw = 0; dw < 3; ++dw) {
                i32x4 a = *(const i32x4*)(sb + a_base + dw * 48);
                acc = __builtin_amdgcn_mfma_i32_32x32x32_i8(a, bfrag[dh * 3 + dw],
                                                            acc, 0, 0, 0);
            }
        }
        float* op = out + ((long)((bimg * 256 + (r0 + i)) * 256 + c0)) * 32 + lrow;
        #pragma unroll
        for (int reg = 0; reg < 16; ++reg) {
            int pr = (reg & 3) + 8 * (reg >> 2) + 4 * lk;
            op[pr * 32] = (float)acc[reg] + bsv;                  // coalesced full lines
        }
    }
}

// ======================= fallback: round-4 fused kernel =======================
#define HSEL(J) ((((J) % 3) == 0) ? h0 : ((((J) % 3) == 1) ? h1 : h2))

#define ISSUE_ROW(J, HREG)                                                      \
    do {                                                                        \
        const int row_  = r0 - 1 + (J);                                         \
        const int rowc_ = row_ < 0 ? 0 : (row_ > 255 ? 255 : row_);             \
        const char* gb_ = (const char*)(x + (long)((bimg * 256 + rowc_) * 256   \
                                                   + c0) * 32);                 \
        unsigned char* lb_ = lds + RAWOFF + ((J) % 3) * RSLOT;                  \
        _Pragma("unroll")                                                       \
        for (int k_ = 0; k_ < 4; ++k_)                                          \
            gload16(gb_ + k_ * 1024 + lswz16, lb_ + k_ * 1024);                 \
        HREG = *(x + (long)(bimg * 256 + rowc_) * 8192 + hoff);                 \
        __builtin_amdgcn_sched_barrier(0);                                      \
    } while (0)

#define PACK_ROW(J, HREG)                                                       \
    do {                                                                        \
        const int row_   = r0 - 1 + (J);                                        \
        const bool rowok_ = (row_ >= 0) && (row_ < 256);                        \
        unsigned char* ps_ = lds + ((J) & 3) * PSLOT;                           \
        const unsigned char* rs_ = lds + RAWOFF + ((J) % 3) * RSLOT;            \
        ps_[hpx * PITCHB + (lane & 31)] =                                       \
            (rowok_ && hok) ? ((HREG >= 0.0f) ? 0x01 : 0xFF) : 0;               \
        uint4 o_;                                                               \
        if (rowok_) {                                                           \
            uint4 w0_ = *(const uint4*)(rs_ + (ppx * 8 + ((ph * 4 + 0) ^ pxr)) * 16); \
            uint4 w1_ = *(const uint4*)(rs_ + (ppx * 8 + ((ph * 4 + 1) ^ pxr)) * 16); \
            uint4 w2_ = *(const uint4*)(rs_ + (ppx * 8 + ((ph * 4 + 2) ^ pxr)) * 16); \
            uint4 w3_ = *(const uint4*)(rs_ + (ppx * 8 + ((ph * 4 + 3) ^ pxr)) * 16); \
            o_ = make_uint4(packsgn4(w0_), packsgn4(w1_),                       \
                            packsgn4(w2_), packsgn4(w3_));                      \
        } else {                                                                \
            o_ = make_uint4(0u, 0u, 0u, 0u);                                    \
        }                                                                       \
        *(uint4*)(ps_ + (ppx + 1) * PITCHB + ph * 16) = o_;                     \
    } while (0)

__global__ __launch_bounds__(64, 2) void conv_fused(const float* __restrict__ x,
                                                    const signed char* __restrict__ wsT,
                                                    const float* __restrict__ bsum,
                                                    float* __restrict__ out) {
    __shared__ __align__(16) unsigned char lds[4 * PSLOT + 3 * RSLOT];

    const int lane = threadIdx.x;
    const int lrow = lane & 31;
    const int lk   = lane >> 5;

    const int bs   = blockIdx.x;
    const int c0   = (bs & 7) * 32;
    const int r0   = ((bs >> 3) & 31) * RH;
    const int bimg = bs >> 8;

    i32x4 bfrag[9];
    #pragma unroll
    for (int t = 0; t < 9; ++t)
        bfrag[t] = *(const i32x4*)(wsT + lrow * 288 + t * 32 + lk * 16);
    const float bsv = bsum[lrow];

    const int lswz16 = (lane ^ ((lane >> 3) & 7)) * 16;
    const int hcol   = (lane < 32) ? (c0 > 0 ? c0 - 1 : 0)
                                   : (c0 + 32 < 256 ? c0 + 32 : 255);
    const bool hok   = (lane < 32) ? (c0 > 0) : (c0 + 32 < 256);
    const int  hpx   = (lane < 32) ? 0 : 33;
    const long hoff  = (long)hcol * 32 + (lane & 31);
    const int  ppx   = lane >> 1;
    const int  ph    = lane & 1;
    const int  pxr   = ppx & 7;

    float h0 = 0.f, h1 = 0.f, h2 = 0.f;

    ISSUE_ROW(0, HSEL(0));
    ISSUE_ROW(1, HSEL(1));
    ISSUE_ROW(2, HSEL(2));
    WAITV(10);  PACK_ROW(0, HSEL(0));
    WAITV(5);   PACK_ROW(1, HSEL(1));
    ISSUE_ROW(3, HSEL(3));
    WAITV(5);   PACK_ROW(2, HSEL(2));

    const int a_off = lrow * PITCHB + lk * 16;

    #pragma unroll
    for (int i = 0; i < RH; ++i) {
        if (i <= RH - 3) ISSUE_ROW(i + 4, HSEL(i + 4));

        if (i == 0)      { WAITV(5);  }
        else if (i <= 5) { WAITV(21); }
        else if (i == 6) { WAITV(16); }
        if (i <= RH - 2) PACK_ROW(i + 3, HSEL(i + 3));

        i32x16 acc = {};
        #pragma unroll
        for (int dh = 0; dh < 3; ++dh) {
            const unsigned char* sb = lds + ((i + dh) & 3) * PSLOT + a_off;
            #pragma unroll
            for (int dw = 0; dw < 3; ++dw) {
                i32x4 a = *(const i32x4*)(sb + dw * PITCHB);
                acc = __builtin_amdgcn_mfma_i32_32x32x32_i8(a, bfrag[dh * 3 + dw],
                                                            acc, 0, 0, 0);
            }
        }

        float* op = out + ((long)((bimg * 256 + (r0 + i)) * 256 + c0)) * 32 + lrow;
        #pragma unroll
        for (int reg = 0; reg < 16; ++reg) {
            int pr = (reg & 3) + 8 * (reg >> 2) + 4 * lk;
            op[pr * 32] = (float)acc[reg] + bsv;
        }
    }
}

extern "C" void kernel_launch(void* const* d_in, const int* in_sizes, int n_in,
                              void* d_out, int out_size, void* d_ws, size_t ws_size,
                              hipStream_t stream) {
    const float* x    = (const float*)d_in[0];   // [16,256,256,32]
    const float* W    = (const float*)d_in[1];   // [4,3,3,32,32]
    const float* bias = (const float*)d_in[2];   // [4,32]
    float* out = (float*)d_out;

    signed char* wsT  = (signed char*)d_ws;                 // 9216 B
    float* bsum       = (float*)((char*)d_ws + 9216);       // 32 f32
    unsigned char* xq = (unsigned char*)d_ws + XQOFF;       // 50.3 MB packed signs

    prep_kernel<<<36, 256, 0, stream>>>(W, bias, wsT, bsum);
    if (ws_size >= (size_t)WSNEED) {
        pack_kernel<<<8192, 256, 0, stream>>>(x, xq);
        conv_batch<<<4096, 64, 0, stream>>>(xq, wsT, bsum, out);
    } else {
        conv_fused<<<4096, 64, 0, stream>>>(x, wsT, bsum, out);
    }
}